// Round 15
// baseline (466.276 us; speedup 1.0000x reference)
//
#include <hip/hip_runtime.h>

#define HDIM 128
#define RDIM 64
#define NLAYERS 3
#define CAP 64   // bucket slots/node: max indeg 63 + self-loop (Poisson(16): P~1e-20)

typedef unsigned int uint32;
typedef unsigned short ushort16;

typedef __attribute__((ext_vector_type(8))) short s16x8;   // 8 bf16 (4 VGPR)
typedef __attribute__((ext_vector_type(4))) float f32x4;   // MFMA acc

union U4 { uint4 u; s16x8 v; };

// round-to-nearest-even fp32 -> bf16 (as raw ushort)
__device__ __forceinline__ ushort16 f2bf_rne(float x) {
  uint32 u = __float_as_uint(x);
  u += 0x7FFFu + ((u >> 16) & 1u);
  return (ushort16)(u >> 16);
}
__device__ __forceinline__ float bf_lo(uint32 p) { return __uint_as_float(p << 16); }
__device__ __forceinline__ float bf_hi(uint32 p) { return __uint_as_float(p & 0xFFFF0000u); }

// ---------------------------------------------------------------------------
// Merged setup: blocks 0-2 repack W(l) to fragment order; 3-5 repack lwT(l);
// the rest zero cursor. Fragment order: element (k,c) of W^T lands at
// [(nc*4+ks)*64+kg*16+lr]*8+ko so a wave's 16B/lane fragment load is one
// contiguous 1KB L2-broadcast hit.
// ---------------------------------------------------------------------------
__global__ void k_setup(const float* __restrict__ Ws, ushort16* __restrict__ Wth,
                        ushort16* __restrict__ Wtl, const float* __restrict__ lw,
                        ushort16* __restrict__ Lh, ushort16* __restrict__ Ll,
                        int* __restrict__ cursor, int n) {
  const int b = blockIdx.x;
  if (b < NLAYERS) {                       // W repack, layer b
    const int lyr = b;
    const float* W = Ws + (size_t)lyr * HDIM * HDIM;
    ushort16* th = Wth + (size_t)lyr * HDIM * HDIM;
    ushort16* tl = Wtl + (size_t)lyr * HDIM * HDIM;
    for (int idx = threadIdx.x; idx < HDIM * HDIM; idx += blockDim.x) {
      int k = idx >> 7, c = idx & 127;     // W[k][c] -> W^T[c][k]
      float w = W[idx];
      uint32 u = __float_as_uint(w);
      uint32 r = u + 0x7FFFu + ((u >> 16) & 1u);
      float hf = __uint_as_float((r >> 16) << 16);
      int nc = c >> 4, lr = c & 15, ks = k >> 5, kg = (k >> 3) & 3, ko = k & 7;
      int dst = (((nc * 4 + ks) * 64) + kg * 16 + lr) * 8 + ko;
      th[dst] = (ushort16)(r >> 16);
      tl[dst] = f2bf_rne(w - hf);
    }
  } else if (b < 2 * NLAYERS) {            // lwT repack, layer b-3
    const int lyr = b - NLAYERS;
    ushort16* th = Lh + (size_t)lyr * RDIM * HDIM;
    ushort16* tl = Ll + (size_t)lyr * RDIM * HDIM;
    for (int idx = threadIdx.x; idx < HDIM * RDIM; idx += blockDim.x) {
      int k = idx >> 6, r = idx & 63;
      float w = lw[(size_t)(lyr * HDIM + k) * RDIM + r];
      uint32 u = __float_as_uint(w);
      uint32 rr = u + 0x7FFFu + ((u >> 16) & 1u);
      float hf = __uint_as_float((rr >> 16) << 16);
      int nc = r >> 4, lr = r & 15, ks = k >> 5, kg = (k >> 3) & 3, ko = k & 7;
      int dst = (((nc * 4 + ks) * 64) + kg * 16 + lr) * 8 + ko;
      th[dst] = (ushort16)(rr >> 16);
      tl[dst] = f2bf_rne(w - hf);
    }
  } else {                                 // cursor = 0
    int nb = gridDim.x - 2 * NLAYERS;
    int stride = nb * blockDim.x;
    for (int i = (b - 2 * NLAYERS) * blockDim.x + threadIdx.x; i < n; i += stride)
      cursor[i] = 0;
  }
}

// Bucket fill, WINDOWED (round-9 lesson: window keeps write lines L2-resident).
__global__ void k_fill(const int* __restrict__ src, const int* __restrict__ dst,
                       int* __restrict__ cursor, int* __restrict__ bucket,
                       int e, int lo, int hi) {
  int i0 = (blockIdx.x * blockDim.x + threadIdx.x) * 4;
  if (i0 + 3 < e) {
    int4 d4 = *(const int4*)(dst + i0);
    int4 s4 = *(const int4*)(src + i0);
    if (d4.x >= lo && d4.x < hi) { int p = atomicAdd(&cursor[d4.x], 1); if (p < CAP - 1) bucket[(d4.x << 6) + p] = s4.x; }
    if (d4.y >= lo && d4.y < hi) { int p = atomicAdd(&cursor[d4.y], 1); if (p < CAP - 1) bucket[(d4.y << 6) + p] = s4.y; }
    if (d4.z >= lo && d4.z < hi) { int p = atomicAdd(&cursor[d4.z], 1); if (p < CAP - 1) bucket[(d4.z << 6) + p] = s4.z; }
    if (d4.w >= lo && d4.w < hi) { int p = atomicAdd(&cursor[d4.w], 1); if (p < CAP - 1) bucket[(d4.w << 6) + p] = s4.w; }
  } else {
    for (int i = i0; i < e; ++i) {
      int d = dst[i];
      if (d >= lo && d < hi) { int p = atomicAdd(&cursor[d], 1); if (p < CAP - 1) bucket[(d << 6) + p] = src[i]; }
    }
  }
}

// Append self-loop, finalize len (cursor <- deg incl. self-loop), dis.
__global__ void k_post(int* __restrict__ cursor, int* __restrict__ bucket,
                       float* __restrict__ dis, int n) {
  int i = blockIdx.x * blockDim.x + threadIdx.x;
  if (i < n) {
    int c = cursor[i];
    if (c > CAP - 1) c = CAP - 1;
    bucket[(i << 6) + c] = i;
    cursor[i] = c + 1;
    dis[i] = rsqrtf((float)(c + 1));
  }
}

// ---------------------------------------------------------------------------
// Split-precision bf16 MFMA GEMM, LDS-FREE: t' = (A @ W) * dis[row], bf16 out.
// ABF16=false (layer 0, fp32 x): 3-term split, 16 rows/wave (proven shape;
//   higher reg pressure from the split).
// ABF16=true (bf16 h): exact 2-term, round-15: 32 rows/wave (2 row-frags
//   share every W fragment load -> half the per-output W L2 traffic, half
//   the waves; the 2 acc chains supply the ILP). ~150 VGPR, 3 waves/SIMD.
// PROJ: 0 = none, 1 = write (+lin_b), 2 = accumulate. (round-14 fusion)
// ---------------------------------------------------------------------------
template <bool ABF16, int PROJ>
__global__ __launch_bounds__(512) void k_gemm_mfma(
    const void* __restrict__ Av, const ushort16* __restrict__ Wth,
    const ushort16* __restrict__ Wtl, ushort16* __restrict__ Cb,
    const float* __restrict__ dis, const ushort16* __restrict__ LwH,
    const ushort16* __restrict__ LwL, const float* __restrict__ lin_b,
    float* __restrict__ Out, int n) {
  constexpr int RF = ABF16 ? 2 : 1;        // row-fragments per wave
  const int tid = threadIdx.x;
  const int wv = tid >> 6;                 // 0..7
  const int l = tid & 63;
  const int lr = l & 15;                   // A-row / B-col within fragment
  const int kg = l >> 4;                   // k-group (8 elems each)
  const int row0 = blockIdx.x * (128 * RF);
  const int wbase = row0 + wv * (16 * RF);

  U4 ahi[RF][4], alo[RF][4];
  if (ABF16) {
#pragma unroll
    for (int rf = 0; rf < RF; ++rf) {
      int arow = wbase + rf * 16 + lr;
      if (arow < n) {
        const ushort16* ap = (const ushort16*)Av + (size_t)arow * HDIM + kg * 8;
#pragma unroll
        for (int ks = 0; ks < 4; ++ks)
          ahi[rf][ks].u = *(const uint4*)(ap + ks * 32);
      } else {
#pragma unroll
        for (int ks = 0; ks < 4; ++ks)
          ahi[rf][ks].u = make_uint4(0, 0, 0, 0);
      }
    }
  } else {
    // fp32 A: load 4 ksteps x 8 fp32, split to bf16 hi/lo
    const float* A = (const float*)Av;
    int arow = wbase + lr;
    float4 av[4][2];
    if (arow < n) {
      const float* ap = A + (size_t)arow * HDIM + kg * 8;
#pragma unroll
      for (int ks = 0; ks < 4; ++ks) {
        av[ks][0] = *(const float4*)(ap + ks * 32);
        av[ks][1] = *(const float4*)(ap + ks * 32 + 4);
      }
    } else {
#pragma unroll
      for (int ks = 0; ks < 4; ++ks)
        av[ks][0] = av[ks][1] = make_float4(0.f, 0.f, 0.f, 0.f);
    }
#pragma unroll
    for (int ks = 0; ks < 4; ++ks) {
      float f[8] = {av[ks][0].x, av[ks][0].y, av[ks][0].z, av[ks][0].w,
                    av[ks][1].x, av[ks][1].y, av[ks][1].z, av[ks][1].w};
      uint32 h[8], lo[8];
#pragma unroll
      for (int j = 0; j < 8; ++j) {
        uint32 u = __float_as_uint(f[j]);
        uint32 r = u + 0x7FFFu + ((u >> 16) & 1u);
        h[j] = r >> 16;
        float hf = __uint_as_float((r >> 16) << 16);
        lo[j] = (uint32)f2bf_rne(f[j] - hf);
      }
      ahi[0][ks].u = make_uint4(h[0] | (h[1] << 16), h[2] | (h[3] << 16),
                                h[4] | (h[5] << 16), h[6] | (h[7] << 16));
      alo[0][ks].u = make_uint4(lo[0] | (lo[1] << 16), lo[2] | (lo[3] << 16),
                                lo[4] | (lo[5] << 16), lo[6] | (lo[7] << 16));
    }
  }

  // ---- fused projection of A rows (h_{l-1} @ lwT_{l-1}) into Out ----
  if (PROJ) {
    const uint4* LH4 = (const uint4*)LwH;
    const uint4* LL4 = (const uint4*)LwL;
#pragma unroll
    for (int nc = 0; nc < 4; ++nc) {
      f32x4 pacc[RF];
#pragma unroll
      for (int rf = 0; rf < RF; ++rf) pacc[rf] = (f32x4){0.f, 0.f, 0.f, 0.f};
      U4 bh[4], bl[4];
      const int b0 = nc * 4 * 64 + l;
#pragma unroll
      for (int ks = 0; ks < 4; ++ks) {
        bh[ks].u = LH4[b0 + ks * 64];
        bl[ks].u = LL4[b0 + ks * 64];
      }
#pragma unroll
      for (int ks = 0; ks < 4; ++ks) {
#pragma unroll
        for (int rf = 0; rf < RF; ++rf) {
          pacc[rf] = __builtin_amdgcn_mfma_f32_16x16x32_bf16(ahi[rf][ks].v, bh[ks].v, pacc[rf], 0, 0, 0);
          pacc[rf] = __builtin_amdgcn_mfma_f32_16x16x32_bf16(ahi[rf][ks].v, bl[ks].v, pacc[rf], 0, 0, 0);
        }
      }
      float lbv = (PROJ == 1) ? lin_b[nc * 16 + lr] : 0.f;
#pragma unroll
      for (int rf = 0; rf < RF; ++rf) {
#pragma unroll
        for (int j = 0; j < 4; ++j) {      // C/D: row=kg*4+j, col=lr
          int grow = wbase + rf * 16 + kg * 4 + j;
          if (grow < n) {
            float* op = Out + (size_t)grow * RDIM + nc * 16 + lr;
            if (PROJ == 1) *op = pacc[rf][j] + lbv;
            else           *op += pacc[rf][j];
          }
        }
      }
    }
  }

  // dis for this lane's output rows
  float dsv[RF][4];
#pragma unroll
  for (int rf = 0; rf < RF; ++rf)
#pragma unroll
    for (int j = 0; j < 4; ++j) {
      int grow = wbase + rf * 16 + kg * 4 + j;
      dsv[rf][j] = (grow < n) ? dis[grow] : 0.f;
    }

  const uint4* WH4 = (const uint4*)Wth;
  const uint4* WL4 = (const uint4*)Wtl;

  f32x4 acc[RF][8];
#pragma unroll
  for (int rf = 0; rf < RF; ++rf)
#pragma unroll
    for (int nc = 0; nc < 8; ++nc) acc[rf][nc] = (f32x4){0.f, 0.f, 0.f, 0.f};

  // ---- MFMA main: W frags via contiguous L2-broadcast loads ----
  if (ABF16) {
    // single-nc, RF=2: the two row-frag chains supply ILP; W live = 32 VGPR
#pragma unroll
    for (int nc = 0; nc < 8; ++nc) {
      U4 wh[4], wl[4];
      const int b0 = nc * 4 * 64 + l;
#pragma unroll
      for (int ks = 0; ks < 4; ++ks) {
        wh[ks].u = WH4[b0 + ks * 64];
        wl[ks].u = WL4[b0 + ks * 64];
      }
#pragma unroll
      for (int ks = 0; ks < 4; ++ks) {
#pragma unroll
        for (int rf = 0; rf < RF; ++rf) {
          acc[rf][nc] = __builtin_amdgcn_mfma_f32_16x16x32_bf16(ahi[rf][ks].v, wh[ks].v, acc[rf][nc], 0, 0, 0);
          acc[rf][nc] = __builtin_amdgcn_mfma_f32_16x16x32_bf16(ahi[rf][ks].v, wl[ks].v, acc[rf][nc], 0, 0, 0);
        }
      }
    }
  } else {
    // paired-nc, RF=1 (proven round-12 shape): 2 acc chains for ILP
#pragma unroll
    for (int nc = 0; nc < 8; nc += 2) {
      U4 w0h[4], w0l[4], w1h[4], w1l[4];
      const int b0 = nc * 4 * 64 + l;
      const int b1 = (nc + 1) * 4 * 64 + l;
#pragma unroll
      for (int ks = 0; ks < 4; ++ks) {
        w0h[ks].u = WH4[b0 + ks * 64];
        w0l[ks].u = WL4[b0 + ks * 64];
        w1h[ks].u = WH4[b1 + ks * 64];
        w1l[ks].u = WL4[b1 + ks * 64];
      }
#pragma unroll
      for (int ks = 0; ks < 4; ++ks) {
        acc[0][nc]     = __builtin_amdgcn_mfma_f32_16x16x32_bf16(ahi[0][ks].v, w0h[ks].v, acc[0][nc],     0, 0, 0);
        acc[0][nc + 1] = __builtin_amdgcn_mfma_f32_16x16x32_bf16(ahi[0][ks].v, w1h[ks].v, acc[0][nc + 1], 0, 0, 0);
        acc[0][nc]     = __builtin_amdgcn_mfma_f32_16x16x32_bf16(alo[0][ks].v, w0h[ks].v, acc[0][nc],     0, 0, 0);
        acc[0][nc + 1] = __builtin_amdgcn_mfma_f32_16x16x32_bf16(alo[0][ks].v, w1h[ks].v, acc[0][nc + 1], 0, 0, 0);
        acc[0][nc]     = __builtin_amdgcn_mfma_f32_16x16x32_bf16(ahi[0][ks].v, w0l[ks].v, acc[0][nc],     0, 0, 0);
        acc[0][nc + 1] = __builtin_amdgcn_mfma_f32_16x16x32_bf16(ahi[0][ks].v, w1l[ks].v, acc[0][nc + 1], 0, 0, 0);
      }
    }
  }

  // ---- direct store: x dis, fp32 -> bf16 (C/D: row=kg*4+j, col=lr) ----
#pragma unroll
  for (int rf = 0; rf < RF; ++rf) {
#pragma unroll
    for (int j = 0; j < 4; ++j) {
      int grow = wbase + rf * 16 + kg * 4 + j;
      if (grow < n) {
        ushort16* op = Cb + (size_t)grow * HDIM + lr;
#pragma unroll
        for (int nc = 0; nc < 8; ++nc)
          op[nc * 16] = f2bf_rne(acc[rf][nc][j] * dsv[rf][j]);
      }
    }
  }
}

// ---------------------------------------------------------------------------
// Standalone MFMA projection for the LAST h: out[rows] += h @ lwT.
// h bf16 -> exact 2-term. Round-15: 32 rows/wave (2 row-frags share B loads).
// ---------------------------------------------------------------------------
__global__ __launch_bounds__(256) void k_proj(const ushort16* __restrict__ A,
                                              const ushort16* __restrict__ LwH,
                                              const ushort16* __restrict__ LwL,
                                              float* __restrict__ Out, int n) {
  const int tid = threadIdx.x;
  const int wv = tid >> 6;
  const int l = tid & 63;
  const int lr = l & 15;
  const int kg = l >> 4;
  const int row0 = blockIdx.x * 128;       // 4 waves x 32 rows
  const int wbase = row0 + wv * 32;

  U4 ahi[2][4];
#pragma unroll
  for (int rf = 0; rf < 2; ++rf) {
    int arow = wbase + rf * 16 + lr;
    if (arow < n) {
      const ushort16* ap = A + (size_t)arow * HDIM + kg * 8;
#pragma unroll
      for (int ks = 0; ks < 4; ++ks)
        ahi[rf][ks].u = *(const uint4*)(ap + ks * 32);
    } else {
#pragma unroll
      for (int ks = 0; ks < 4; ++ks)
        ahi[rf][ks].u = make_uint4(0, 0, 0, 0);
    }
  }

  const uint4* LH4 = (const uint4*)LwH;
  const uint4* LL4 = (const uint4*)LwL;

#pragma unroll
  for (int nc = 0; nc < 4; ++nc) {
    f32x4 pacc[2];
    pacc[0] = (f32x4){0.f, 0.f, 0.f, 0.f};
    pacc[1] = (f32x4){0.f, 0.f, 0.f, 0.f};
    U4 bh[4], bl[4];
    const int b0 = nc * 4 * 64 + l;
#pragma unroll
    for (int ks = 0; ks < 4; ++ks) {
      bh[ks].u = LH4[b0 + ks * 64];
      bl[ks].u = LL4[b0 + ks * 64];
    }
#pragma unroll
    for (int ks = 0; ks < 4; ++ks) {
#pragma unroll
      for (int rf = 0; rf < 2; ++rf) {
        pacc[rf] = __builtin_amdgcn_mfma_f32_16x16x32_bf16(ahi[rf][ks].v, bh[ks].v, pacc[rf], 0, 0, 0);
        pacc[rf] = __builtin_amdgcn_mfma_f32_16x16x32_bf16(ahi[rf][ks].v, bl[ks].v, pacc[rf], 0, 0, 0);
      }
    }
#pragma unroll
    for (int rf = 0; rf < 2; ++rf) {
#pragma unroll
      for (int j = 0; j < 4; ++j) {
        int grow = wbase + rf * 16 + kg * 4 + j;
        if (grow < n) {
          float* op = Out + (size_t)grow * RDIM + nc * 16 + lr;
          *op += pacc[rf][j];
        }
      }
    }
  }
}

// ---------------------------------------------------------------------------
// Bucket-gather aggregation over bf16 t' (= t * dis[src]). One wave per node;
// quarter-wave (16 lanes x 16B = one 256B bf16 row) per edge. Fetch-bound at
// the random-gather first-touch floor (~193MB/dispatch) — structural for a
// random graph; accepted.
// hout[v] = relu( dis[v] * sum + bias )  stored bf16.
// ---------------------------------------------------------------------------
__global__ __launch_bounds__(256) void k_agg(const ushort16* __restrict__ tb,
                                             const int* __restrict__ len,
                                             const int* __restrict__ bucket,
                                             const float* __restrict__ dis,
                                             const float* __restrict__ bias,
                                             ushort16* __restrict__ hout, int n) {
  const int lane = threadIdx.x & 63;
  const int q = lane >> 4;
  const int fl = (lane & 15) * 8;
  const float4 bv0 = *(const float4*)(bias + fl);
  const float4 bv1 = *(const float4*)(bias + fl + 4);
  const int wid = blockIdx.x * 4 + (threadIdx.x >> 6);
  const int nw = gridDim.x * 4;
  for (int v = wid; v < n; v += nw) {
    const int e0 = v << 6;
    const int e1 = e0 + len[v];
    float a0 = 0.f, a1 = 0.f, a2 = 0.f, a3 = 0.f;
    float a4 = 0.f, a5 = 0.f, a6 = 0.f, a7 = 0.f;
    int e = e0;
    for (; e + 7 < e1; e += 8) {
      int uA = bucket[e + q];
      int uB = bucket[e + 4 + q];
      uint4 ta = *(const uint4*)(tb + ((size_t)uA << 7) + fl);
      uint4 tc = *(const uint4*)(tb + ((size_t)uB << 7) + fl);
      a0 += bf_lo(ta.x); a1 += bf_hi(ta.x);
      a2 += bf_lo(ta.y); a3 += bf_hi(ta.y);
      a4 += bf_lo(ta.z); a5 += bf_hi(ta.z);
      a6 += bf_lo(ta.w); a7 += bf_hi(ta.w);
      a0 += bf_lo(tc.x); a1 += bf_hi(tc.x);
      a2 += bf_lo(tc.y); a3 += bf_hi(tc.y);
      a4 += bf_lo(tc.z); a5 += bf_hi(tc.z);
      a6 += bf_lo(tc.w); a7 += bf_hi(tc.w);
    }
    for (; e < e1; e += 4) {
      int idx = e + q;
      if (idx < e1) {
        int u = bucket[idx];
        uint4 ta = *(const uint4*)(tb + ((size_t)u << 7) + fl);
        a0 += bf_lo(ta.x); a1 += bf_hi(ta.x);
        a2 += bf_lo(ta.y); a3 += bf_hi(ta.y);
        a4 += bf_lo(ta.z); a5 += bf_hi(ta.z);
        a6 += bf_lo(ta.w); a7 += bf_hi(ta.w);
      }
    }
    a0 += __shfl_xor(a0, 32); a1 += __shfl_xor(a1, 32);
    a2 += __shfl_xor(a2, 32); a3 += __shfl_xor(a3, 32);
    a4 += __shfl_xor(a4, 32); a5 += __shfl_xor(a5, 32);
    a6 += __shfl_xor(a6, 32); a7 += __shfl_xor(a7, 32);
    a0 += __shfl_xor(a0, 16); a1 += __shfl_xor(a1, 16);
    a2 += __shfl_xor(a2, 16); a3 += __shfl_xor(a3, 16);
    a4 += __shfl_xor(a4, 16); a5 += __shfl_xor(a5, 16);
    a6 += __shfl_xor(a6, 16); a7 += __shfl_xor(a7, 16);
    if (q == 0) {
      const float dv = dis[v];
      float h0 = fmaxf(fmaf(a0, dv, bv0.x), 0.f);
      float h1 = fmaxf(fmaf(a1, dv, bv0.y), 0.f);
      float h2 = fmaxf(fmaf(a2, dv, bv0.z), 0.f);
      float h3 = fmaxf(fmaf(a3, dv, bv0.w), 0.f);
      float h4 = fmaxf(fmaf(a4, dv, bv1.x), 0.f);
      float h5 = fmaxf(fmaf(a5, dv, bv1.y), 0.f);
      float h6 = fmaxf(fmaf(a6, dv, bv1.z), 0.f);
      float h7 = fmaxf(fmaf(a7, dv, bv1.w), 0.f);
      uint4 pk;
      pk.x = (uint32)f2bf_rne(h0) | ((uint32)f2bf_rne(h1) << 16);
      pk.y = (uint32)f2bf_rne(h2) | ((uint32)f2bf_rne(h3) << 16);
      pk.z = (uint32)f2bf_rne(h4) | ((uint32)f2bf_rne(h5) << 16);
      pk.w = (uint32)f2bf_rne(h6) | ((uint32)f2bf_rne(h7) << 16);
      *(uint4*)(hout + (size_t)v * HDIM + fl) = pk;
    }
  }
}

// ---------------------------------------------------------------------------
extern "C" void kernel_launch(void* const* d_in, const int* in_sizes, int n_in,
                              void* d_out, int out_size, void* d_ws, size_t ws_size,
                              hipStream_t stream) {
  (void)n_in; (void)out_size; (void)ws_size;
  const float* x  = (const float*)d_in[0];
  const int*   ei = (const int*)d_in[1];
  const float* Ws = (const float*)d_in[2];
  const float* bs = (const float*)d_in[3];
  const float* lw = (const float*)d_in[4];
  const float* lb = (const float*)d_in[5];
  float* out = (float*)d_out;

  const int n = in_sizes[0] / HDIM;
  const int e = in_sizes[1] / 2;
  const int* src = ei;
  const int* dst = ei + e;

  // workspace carve-out (~80 MB)
  char* p = (char*)d_ws;
  auto take = [&](size_t bytes) {
    char* r = p;
    p += (bytes + 255) & ~(size_t)255;
    return (void*)r;
  };
  int*      cursor = (int*)take((size_t)n * 4);
  float*    dis    = (float*)take((size_t)n * 4);
  int*      bucket = (int*)take((size_t)n * CAP * 4);              // 25.6 MB
  ushort16* tbuf   = (ushort16*)take((size_t)n * HDIM * 2);        // bf16 t'
  ushort16* hbuf   = (ushort16*)take((size_t)n * HDIM * 2);        // bf16 h
  ushort16* wth    = (ushort16*)take((size_t)NLAYERS * HDIM * HDIM * 2);
  ushort16* wtl    = (ushort16*)take((size_t)NLAYERS * HDIM * HDIM * 2);
  ushort16* lwth   = (ushort16*)take((size_t)NLAYERS * RDIM * HDIM * 2);
  ushort16* lwtl   = (ushort16*)take((size_t)NLAYERS * RDIM * HDIM * 2);

  // merged setup (W/lwT repack + cursor zero) + bucket CSR build
  k_setup<<<2 * NLAYERS + 128, 256, 0, stream>>>(Ws, wth, wtl, lw, lwth, lwtl,
                                                 cursor, n);
  {
    const int PASSES = 4;
    const int rng = (n + PASSES - 1) / PASSES;
    const int fgrid = ((e + 3) / 4 + 255) / 256;
    for (int ps = 0; ps < PASSES; ++ps) {
      int lo = ps * rng;
      int hi = lo + rng < n ? lo + rng : n;
      k_fill<<<fgrid, 256, 0, stream>>>(src, dst, cursor, bucket, e, lo, hi);
    }
  }
  k_post<<<(n + 255) / 256, 256, 0, stream>>>(cursor, bucket, dis, n);

  // 3 GCN layers. proj(h_l) fused into gemm(l+1); proj(h_3) standalone.
  const int gtiles0 = (n + 127) / 128;   // layer-0 gemm: 128 rows/block
  const int gtiles1 = (n + 255) / 256;   // bf16 gemms: 256 rows/block
  const int ptiles  = (n + 127) / 128;   // proj: 128 rows/block
  k_gemm_mfma<false, 0><<<gtiles0, 512, 0, stream>>>(
      x, wth, wtl, tbuf, dis, nullptr, nullptr, nullptr, nullptr, n);
  k_agg<<<2048, 256, 0, stream>>>(tbuf, cursor, bucket, dis, bs, hbuf, n);
  k_gemm_mfma<true, 1><<<gtiles1, 512, 0, stream>>>(
      hbuf, wth + (size_t)1 * HDIM * HDIM, wtl + (size_t)1 * HDIM * HDIM,
      tbuf, dis, lwth, lwtl, lb, out, n);
  k_agg<<<2048, 256, 0, stream>>>(
      tbuf, cursor, bucket, dis, bs + (size_t)1 * HDIM, hbuf, n);
  k_gemm_mfma<true, 2><<<gtiles1, 512, 0, stream>>>(
      hbuf, wth + (size_t)2 * HDIM * HDIM, wtl + (size_t)2 * HDIM * HDIM,
      tbuf, dis, lwth + (size_t)1 * RDIM * HDIM, lwtl + (size_t)1 * RDIM * HDIM,
      nullptr, out, n);
  k_agg<<<2048, 256, 0, stream>>>(
      tbuf, cursor, bucket, dis, bs + (size_t)2 * HDIM, hbuf, n);
  k_proj<<<ptiles, 256, 0, stream>>>(
      hbuf, lwth + (size_t)2 * RDIM * HDIM, lwtl + (size_t)2 * RDIM * HDIM,
      out, n);
}

// Round 16
// 442.818 us; speedup vs baseline: 1.0530x; 1.0530x over previous
//
#include <hip/hip_runtime.h>

#define HDIM 128
#define RDIM 64
#define NLAYERS 3
#define CAP 64   // bucket slots/node: max indeg 63 + self-loop (Poisson(16): P~1e-20)

typedef unsigned int uint32;
typedef unsigned short ushort16;

typedef __attribute__((ext_vector_type(8))) short s16x8;   // 8 bf16 (4 VGPR)
typedef __attribute__((ext_vector_type(4))) float f32x4;   // MFMA acc

union U4 { uint4 u; s16x8 v; };

// round-to-nearest-even fp32 -> bf16 (as raw ushort)
__device__ __forceinline__ ushort16 f2bf_rne(float x) {
  uint32 u = __float_as_uint(x);
  u += 0x7FFFu + ((u >> 16) & 1u);
  return (ushort16)(u >> 16);
}
__device__ __forceinline__ float bf_lo(uint32 p) { return __uint_as_float(p << 16); }
__device__ __forceinline__ float bf_hi(uint32 p) { return __uint_as_float(p & 0xFFFF0000u); }

// ---------------------------------------------------------------------------
// Merged setup: blocks 0-2 repack W(l) to fragment order; 3-5 repack lwT(l);
// the rest zero cursor. Fragment order: element (k,c) of W^T lands at
// [(nc*4+ks)*64+kg*16+lr]*8+ko so a wave's 16B/lane fragment load is one
// contiguous 1KB L2-broadcast hit.
// ---------------------------------------------------------------------------
__global__ void k_setup(const float* __restrict__ Ws, ushort16* __restrict__ Wth,
                        ushort16* __restrict__ Wtl, const float* __restrict__ lw,
                        ushort16* __restrict__ Lh, ushort16* __restrict__ Ll,
                        int* __restrict__ cursor, int n) {
  const int b = blockIdx.x;
  if (b < NLAYERS) {                       // W repack, layer b
    const int lyr = b;
    const float* W = Ws + (size_t)lyr * HDIM * HDIM;
    ushort16* th = Wth + (size_t)lyr * HDIM * HDIM;
    ushort16* tl = Wtl + (size_t)lyr * HDIM * HDIM;
    for (int idx = threadIdx.x; idx < HDIM * HDIM; idx += blockDim.x) {
      int k = idx >> 7, c = idx & 127;     // W[k][c] -> W^T[c][k]
      float w = W[idx];
      uint32 u = __float_as_uint(w);
      uint32 r = u + 0x7FFFu + ((u >> 16) & 1u);
      float hf = __uint_as_float((r >> 16) << 16);
      int nc = c >> 4, lr = c & 15, ks = k >> 5, kg = (k >> 3) & 3, ko = k & 7;
      int dst = (((nc * 4 + ks) * 64) + kg * 16 + lr) * 8 + ko;
      th[dst] = (ushort16)(r >> 16);
      tl[dst] = f2bf_rne(w - hf);
    }
  } else if (b < 2 * NLAYERS) {            // lwT repack, layer b-3
    const int lyr = b - NLAYERS;
    ushort16* th = Lh + (size_t)lyr * RDIM * HDIM;
    ushort16* tl = Ll + (size_t)lyr * RDIM * HDIM;
    for (int idx = threadIdx.x; idx < HDIM * RDIM; idx += blockDim.x) {
      int k = idx >> 6, r = idx & 63;
      float w = lw[(size_t)(lyr * HDIM + k) * RDIM + r];
      uint32 u = __float_as_uint(w);
      uint32 rr = u + 0x7FFFu + ((u >> 16) & 1u);
      float hf = __uint_as_float((rr >> 16) << 16);
      int nc = r >> 4, lr = r & 15, ks = k >> 5, kg = (k >> 3) & 3, ko = k & 7;
      int dst = (((nc * 4 + ks) * 64) + kg * 16 + lr) * 8 + ko;
      th[dst] = (ushort16)(rr >> 16);
      tl[dst] = f2bf_rne(w - hf);
    }
  } else {                                 // cursor = 0
    int nb = gridDim.x - 2 * NLAYERS;
    int stride = nb * blockDim.x;
    for (int i = (b - 2 * NLAYERS) * blockDim.x + threadIdx.x; i < n; i += stride)
      cursor[i] = 0;
  }
}

// Bucket fill, WINDOWED (round-9 lesson: window keeps write lines L2-resident).
// pos = atomicAdd(cursor) gives slot AND, at the end, the degree.
__global__ void k_fill(const int* __restrict__ src, const int* __restrict__ dst,
                       int* __restrict__ cursor, int* __restrict__ bucket,
                       int e, int lo, int hi) {
  int i0 = (blockIdx.x * blockDim.x + threadIdx.x) * 4;
  if (i0 + 3 < e) {
    int4 d4 = *(const int4*)(dst + i0);
    int4 s4 = *(const int4*)(src + i0);
    if (d4.x >= lo && d4.x < hi) { int p = atomicAdd(&cursor[d4.x], 1); if (p < CAP - 1) bucket[(d4.x << 6) + p] = s4.x; }
    if (d4.y >= lo && d4.y < hi) { int p = atomicAdd(&cursor[d4.y], 1); if (p < CAP - 1) bucket[(d4.y << 6) + p] = s4.y; }
    if (d4.z >= lo && d4.z < hi) { int p = atomicAdd(&cursor[d4.z], 1); if (p < CAP - 1) bucket[(d4.z << 6) + p] = s4.z; }
    if (d4.w >= lo && d4.w < hi) { int p = atomicAdd(&cursor[d4.w], 1); if (p < CAP - 1) bucket[(d4.w << 6) + p] = s4.w; }
  } else {
    for (int i = i0; i < e; ++i) {
      int d = dst[i];
      if (d >= lo && d < hi) { int p = atomicAdd(&cursor[d], 1); if (p < CAP - 1) bucket[(d << 6) + p] = src[i]; }
    }
  }
}

// Append self-loop, finalize len (cursor <- deg incl. self-loop), dis.
__global__ void k_post(int* __restrict__ cursor, int* __restrict__ bucket,
                       float* __restrict__ dis, int n) {
  int i = blockIdx.x * blockDim.x + threadIdx.x;
  if (i < n) {
    int c = cursor[i];
    if (c > CAP - 1) c = CAP - 1;
    bucket[(i << 6) + c] = i;
    cursor[i] = c + 1;
    dis[i] = rsqrtf((float)(c + 1));
  }
}

// ---------------------------------------------------------------------------
// Split-precision bf16 MFMA GEMM, LDS-FREE: t' = (A @ W) * dis[row], bf16 out.
// ABF16=false (layer 0, fp32 x): 3-term split. ABF16=true (bf16 h): exact
// 2-term. 16 rows/wave, 128 rows/block (round-15 lesson: widening rows/wave
// halves block count and REGRESSES — these kernels are latency-bound, wave
// count is the binding resource, W loads are already ~free L2 broadcasts).
// PROJ: 0 = none, 1 = write (+lin_b), 2 = accumulate. (round-14 fusion)
// ---------------------------------------------------------------------------
template <bool ABF16, int PROJ>
__global__ __launch_bounds__(512) void k_gemm_mfma(
    const void* __restrict__ Av, const ushort16* __restrict__ Wth,
    const ushort16* __restrict__ Wtl, ushort16* __restrict__ Cb,
    const float* __restrict__ dis, const ushort16* __restrict__ LwH,
    const ushort16* __restrict__ LwL, const float* __restrict__ lin_b,
    float* __restrict__ Out, int n) {
  const int tid = threadIdx.x;
  const int wv = tid >> 6;         // 0..7
  const int l = tid & 63;
  const int lr = l & 15;           // A-row / B-col within fragment
  const int kg = l >> 4;           // k-group (8 elems each)
  const int row0 = blockIdx.x * 128;
  const int arow = row0 + wv * 16 + lr;

  U4 ahi[4], alo[4];
  if (ABF16) {
    // ---- bf16 A: fragment load directly, no split ----
    if (arow < n) {
      const ushort16* ap = (const ushort16*)Av + (size_t)arow * HDIM + kg * 8;
#pragma unroll
      for (int ks = 0; ks < 4; ++ks)
        ahi[ks].u = *(const uint4*)(ap + ks * 32);
    } else {
#pragma unroll
      for (int ks = 0; ks < 4; ++ks)
        ahi[ks].u = make_uint4(0, 0, 0, 0);
    }
  } else {
    // ---- fp32 A: load 4 ksteps x 8 fp32, split to bf16 hi/lo ----
    const float* A = (const float*)Av;
    float4 av[4][2];
    if (arow < n) {
      const float* ap = A + (size_t)arow * HDIM + kg * 8;
#pragma unroll
      for (int ks = 0; ks < 4; ++ks) {
        av[ks][0] = *(const float4*)(ap + ks * 32);
        av[ks][1] = *(const float4*)(ap + ks * 32 + 4);
      }
    } else {
#pragma unroll
      for (int ks = 0; ks < 4; ++ks)
        av[ks][0] = av[ks][1] = make_float4(0.f, 0.f, 0.f, 0.f);
    }
#pragma unroll
    for (int ks = 0; ks < 4; ++ks) {
      float f[8] = {av[ks][0].x, av[ks][0].y, av[ks][0].z, av[ks][0].w,
                    av[ks][1].x, av[ks][1].y, av[ks][1].z, av[ks][1].w};
      uint32 h[8], lo[8];
#pragma unroll
      for (int j = 0; j < 8; ++j) {
        uint32 u = __float_as_uint(f[j]);
        uint32 r = u + 0x7FFFu + ((u >> 16) & 1u);
        h[j] = r >> 16;
        float hf = __uint_as_float((r >> 16) << 16);
        lo[j] = (uint32)f2bf_rne(f[j] - hf);
      }
      ahi[ks].u = make_uint4(h[0] | (h[1] << 16), h[2] | (h[3] << 16),
                             h[4] | (h[5] << 16), h[6] | (h[7] << 16));
      alo[ks].u = make_uint4(lo[0] | (lo[1] << 16), lo[2] | (lo[3] << 16),
                             lo[4] | (lo[5] << 16), lo[6] | (lo[7] << 16));
    }
  }

  // ---- fused projection of A rows (h_{l-1} @ lwT_{l-1}) into Out ----
  if (PROJ) {
    const uint4* LH4 = (const uint4*)LwH;
    const uint4* LL4 = (const uint4*)LwL;
#pragma unroll
    for (int nc = 0; nc < 4; ++nc) {
      f32x4 pacc = (f32x4){0.f, 0.f, 0.f, 0.f};
      U4 bh[4], bl[4];
      const int b0 = nc * 4 * 64 + l;
#pragma unroll
      for (int ks = 0; ks < 4; ++ks) {
        bh[ks].u = LH4[b0 + ks * 64];
        bl[ks].u = LL4[b0 + ks * 64];
      }
#pragma unroll
      for (int ks = 0; ks < 4; ++ks) {
        pacc = __builtin_amdgcn_mfma_f32_16x16x32_bf16(ahi[ks].v, bh[ks].v, pacc, 0, 0, 0);
        pacc = __builtin_amdgcn_mfma_f32_16x16x32_bf16(ahi[ks].v, bl[ks].v, pacc, 0, 0, 0);
      }
      float lbv = (PROJ == 1) ? lin_b[nc * 16 + lr] : 0.f;
#pragma unroll
      for (int j = 0; j < 4; ++j) {        // C/D: row=kg*4+j, col=lr
        int grow = row0 + wv * 16 + kg * 4 + j;
        if (grow < n) {
          float* op = Out + (size_t)grow * RDIM + nc * 16 + lr;
          if (PROJ == 1) *op = pacc[j] + lbv;
          else           *op += pacc[j];
        }
      }
    }
  }

  // dis for this lane's 4 output rows
  float dsv[4];
#pragma unroll
  for (int j = 0; j < 4; ++j) {
    int grow = row0 + wv * 16 + kg * 4 + j;
    dsv[j] = (grow < n) ? dis[grow] : 0.f;
  }

  const uint4* WH4 = (const uint4*)Wth;
  const uint4* WL4 = (const uint4*)Wtl;

  f32x4 acc[8];
#pragma unroll
  for (int nc = 0; nc < 8; ++nc) acc[nc] = (f32x4){0.f, 0.f, 0.f, 0.f};

  // ---- MFMA main: W frags via contiguous L2-broadcast loads ----
#pragma unroll
  for (int nc = 0; nc < 8; nc += 2) {
    U4 w0h[4], w0l[4], w1h[4], w1l[4];
    const int b0 = nc * 4 * 64 + l;
    const int b1 = (nc + 1) * 4 * 64 + l;
#pragma unroll
    for (int ks = 0; ks < 4; ++ks) {
      w0h[ks].u = WH4[b0 + ks * 64];
      w0l[ks].u = WL4[b0 + ks * 64];
      w1h[ks].u = WH4[b1 + ks * 64];
      w1l[ks].u = WL4[b1 + ks * 64];
    }
#pragma unroll
    for (int ks = 0; ks < 4; ++ks) {
      acc[nc]     = __builtin_amdgcn_mfma_f32_16x16x32_bf16(ahi[ks].v, w0h[ks].v, acc[nc],     0, 0, 0);
      acc[nc + 1] = __builtin_amdgcn_mfma_f32_16x16x32_bf16(ahi[ks].v, w1h[ks].v, acc[nc + 1], 0, 0, 0);
      if (!ABF16) {
        acc[nc]     = __builtin_amdgcn_mfma_f32_16x16x32_bf16(alo[ks].v, w0h[ks].v, acc[nc],     0, 0, 0);
        acc[nc + 1] = __builtin_amdgcn_mfma_f32_16x16x32_bf16(alo[ks].v, w1h[ks].v, acc[nc + 1], 0, 0, 0);
      }
      acc[nc]     = __builtin_amdgcn_mfma_f32_16x16x32_bf16(ahi[ks].v, w0l[ks].v, acc[nc],     0, 0, 0);
      acc[nc + 1] = __builtin_amdgcn_mfma_f32_16x16x32_bf16(ahi[ks].v, w1l[ks].v, acc[nc + 1], 0, 0, 0);
    }
  }

  // ---- direct store: x dis, fp32 -> bf16 (C/D: row=kg*4+j, col=lr) ----
#pragma unroll
  for (int j = 0; j < 4; ++j) {
    int grow = row0 + wv * 16 + kg * 4 + j;
    if (grow < n) {
      ushort16* op = Cb + (size_t)grow * HDIM + lr;
#pragma unroll
      for (int nc = 0; nc < 8; ++nc)
        op[nc * 16] = f2bf_rne(acc[nc][j] * dsv[j]);
    }
  }
}

// ---------------------------------------------------------------------------
// Standalone MFMA projection for the LAST h (no successor gemm to fuse into):
// out[rows] += h @ lwT. h bf16 -> exact 2-term. B frags fragment-ordered.
// 16 rows/wave, 64 rows/block (round-15 lesson: keep block count high).
// ---------------------------------------------------------------------------
__global__ __launch_bounds__(256) void k_proj(const ushort16* __restrict__ A,
                                              const ushort16* __restrict__ LwH,
                                              const ushort16* __restrict__ LwL,
                                              float* __restrict__ Out, int n) {
  const int tid = threadIdx.x;
  const int wv = tid >> 6;
  const int l = tid & 63;
  const int lr = l & 15;
  const int kg = l >> 4;
  const int row0 = blockIdx.x * 64;
  const int arow = row0 + wv * 16 + lr;

  U4 ahi[4];
  if (arow < n) {
    const ushort16* ap = A + (size_t)arow * HDIM + kg * 8;
#pragma unroll
    for (int ks = 0; ks < 4; ++ks)
      ahi[ks].u = *(const uint4*)(ap + ks * 32);
  } else {
#pragma unroll
    for (int ks = 0; ks < 4; ++ks)
      ahi[ks].u = make_uint4(0, 0, 0, 0);
  }

  const uint4* LH4 = (const uint4*)LwH;
  const uint4* LL4 = (const uint4*)LwL;

#pragma unroll
  for (int nc = 0; nc < 4; ++nc) {
    f32x4 pacc = (f32x4){0.f, 0.f, 0.f, 0.f};
    U4 bh[4], bl[4];
    const int b0 = nc * 4 * 64 + l;
#pragma unroll
    for (int ks = 0; ks < 4; ++ks) {
      bh[ks].u = LH4[b0 + ks * 64];
      bl[ks].u = LL4[b0 + ks * 64];
    }
#pragma unroll
    for (int ks = 0; ks < 4; ++ks) {
      pacc = __builtin_amdgcn_mfma_f32_16x16x32_bf16(ahi[ks].v, bh[ks].v, pacc, 0, 0, 0);
      pacc = __builtin_amdgcn_mfma_f32_16x16x32_bf16(ahi[ks].v, bl[ks].v, pacc, 0, 0, 0);
    }
#pragma unroll
    for (int j = 0; j < 4; ++j) {
      int grow = row0 + wv * 16 + kg * 4 + j;
      if (grow < n) {
        float* op = Out + (size_t)grow * RDIM + nc * 16 + lr;
        *op += pacc[j];
      }
    }
  }
}

// ---------------------------------------------------------------------------
// Bucket-gather aggregation over bf16 t' (= t * dis[src]). One wave per node;
// quarter-wave (16 lanes x 16B = one 256B bf16 row) per edge. Fetch-bound at
// the random-gather first-touch floor (~193MB/dispatch at ~3.4TB/s) —
// structural for a random graph; accepted.
// hout[v] = relu( dis[v] * sum + bias )  stored bf16.
// ---------------------------------------------------------------------------
__global__ __launch_bounds__(256) void k_agg(const ushort16* __restrict__ tb,
                                             const int* __restrict__ len,
                                             const int* __restrict__ bucket,
                                             const float* __restrict__ dis,
                                             const float* __restrict__ bias,
                                             ushort16* __restrict__ hout, int n) {
  const int lane = threadIdx.x & 63;
  const int q = lane >> 4;
  const int fl = (lane & 15) * 8;
  const float4 bv0 = *(const float4*)(bias + fl);
  const float4 bv1 = *(const float4*)(bias + fl + 4);
  const int wid = blockIdx.x * 4 + (threadIdx.x >> 6);
  const int nw = gridDim.x * 4;
  for (int v = wid; v < n; v += nw) {
    const int e0 = v << 6;
    const int e1 = e0 + len[v];
    float a0 = 0.f, a1 = 0.f, a2 = 0.f, a3 = 0.f;
    float a4 = 0.f, a5 = 0.f, a6 = 0.f, a7 = 0.f;
    int e = e0;
    for (; e + 7 < e1; e += 8) {
      int uA = bucket[e + q];
      int uB = bucket[e + 4 + q];
      uint4 ta = *(const uint4*)(tb + ((size_t)uA << 7) + fl);
      uint4 tc = *(const uint4*)(tb + ((size_t)uB << 7) + fl);
      a0 += bf_lo(ta.x); a1 += bf_hi(ta.x);
      a2 += bf_lo(ta.y); a3 += bf_hi(ta.y);
      a4 += bf_lo(ta.z); a5 += bf_hi(ta.z);
      a6 += bf_lo(ta.w); a7 += bf_hi(ta.w);
      a0 += bf_lo(tc.x); a1 += bf_hi(tc.x);
      a2 += bf_lo(tc.y); a3 += bf_hi(tc.y);
      a4 += bf_lo(tc.z); a5 += bf_hi(tc.z);
      a6 += bf_lo(tc.w); a7 += bf_hi(tc.w);
    }
    for (; e < e1; e += 4) {
      int idx = e + q;
      if (idx < e1) {
        int u = bucket[idx];
        uint4 ta = *(const uint4*)(tb + ((size_t)u << 7) + fl);
        a0 += bf_lo(ta.x); a1 += bf_hi(ta.x);
        a2 += bf_lo(ta.y); a3 += bf_hi(ta.y);
        a4 += bf_lo(ta.z); a5 += bf_hi(ta.z);
        a6 += bf_lo(ta.w); a7 += bf_hi(ta.w);
      }
    }
    a0 += __shfl_xor(a0, 32); a1 += __shfl_xor(a1, 32);
    a2 += __shfl_xor(a2, 32); a3 += __shfl_xor(a3, 32);
    a4 += __shfl_xor(a4, 32); a5 += __shfl_xor(a5, 32);
    a6 += __shfl_xor(a6, 32); a7 += __shfl_xor(a7, 32);
    a0 += __shfl_xor(a0, 16); a1 += __shfl_xor(a1, 16);
    a2 += __shfl_xor(a2, 16); a3 += __shfl_xor(a3, 16);
    a4 += __shfl_xor(a4, 16); a5 += __shfl_xor(a5, 16);
    a6 += __shfl_xor(a6, 16); a7 += __shfl_xor(a7, 16);
    if (q == 0) {
      const float dv = dis[v];
      float h0 = fmaxf(fmaf(a0, dv, bv0.x), 0.f);
      float h1 = fmaxf(fmaf(a1, dv, bv0.y), 0.f);
      float h2 = fmaxf(fmaf(a2, dv, bv0.z), 0.f);
      float h3 = fmaxf(fmaf(a3, dv, bv0.w), 0.f);
      float h4 = fmaxf(fmaf(a4, dv, bv1.x), 0.f);
      float h5 = fmaxf(fmaf(a5, dv, bv1.y), 0.f);
      float h6 = fmaxf(fmaf(a6, dv, bv1.z), 0.f);
      float h7 = fmaxf(fmaf(a7, dv, bv1.w), 0.f);
      uint4 pk;
      pk.x = (uint32)f2bf_rne(h0) | ((uint32)f2bf_rne(h1) << 16);
      pk.y = (uint32)f2bf_rne(h2) | ((uint32)f2bf_rne(h3) << 16);
      pk.z = (uint32)f2bf_rne(h4) | ((uint32)f2bf_rne(h5) << 16);
      pk.w = (uint32)f2bf_rne(h6) | ((uint32)f2bf_rne(h7) << 16);
      *(uint4*)(hout + (size_t)v * HDIM + fl) = pk;
    }
  }
}

// ---------------------------------------------------------------------------
extern "C" void kernel_launch(void* const* d_in, const int* in_sizes, int n_in,
                              void* d_out, int out_size, void* d_ws, size_t ws_size,
                              hipStream_t stream) {
  (void)n_in; (void)out_size; (void)ws_size;
  const float* x  = (const float*)d_in[0];
  const int*   ei = (const int*)d_in[1];
  const float* Ws = (const float*)d_in[2];
  const float* bs = (const float*)d_in[3];
  const float* lw = (const float*)d_in[4];
  const float* lb = (const float*)d_in[5];
  float* out = (float*)d_out;

  const int n = in_sizes[0] / HDIM;
  const int e = in_sizes[1] / 2;
  const int* src = ei;
  const int* dst = ei + e;

  // workspace carve-out (~80 MB)
  char* p = (char*)d_ws;
  auto take = [&](size_t bytes) {
    char* r = p;
    p += (bytes + 255) & ~(size_t)255;
    return (void*)r;
  };
  int*      cursor = (int*)take((size_t)n * 4);
  float*    dis    = (float*)take((size_t)n * 4);
  int*      bucket = (int*)take((size_t)n * CAP * 4);              // 25.6 MB
  ushort16* tbuf   = (ushort16*)take((size_t)n * HDIM * 2);        // bf16 t'
  ushort16* hbuf   = (ushort16*)take((size_t)n * HDIM * 2);        // bf16 h
  ushort16* wth    = (ushort16*)take((size_t)NLAYERS * HDIM * HDIM * 2);
  ushort16* wtl    = (ushort16*)take((size_t)NLAYERS * HDIM * HDIM * 2);
  ushort16* lwth   = (ushort16*)take((size_t)NLAYERS * RDIM * HDIM * 2);
  ushort16* lwtl   = (ushort16*)take((size_t)NLAYERS * RDIM * HDIM * 2);

  // merged setup (W/lwT repack + cursor zero) + bucket CSR build
  k_setup<<<2 * NLAYERS + 128, 256, 0, stream>>>(Ws, wth, wtl, lw, lwth, lwtl,
                                                 cursor, n);
  {
    const int PASSES = 4;
    const int rng = (n + PASSES - 1) / PASSES;
    const int fgrid = ((e + 3) / 4 + 255) / 256;
    for (int ps = 0; ps < PASSES; ++ps) {
      int lo = ps * rng;
      int hi = lo + rng < n ? lo + rng : n;
      k_fill<<<fgrid, 256, 0, stream>>>(src, dst, cursor, bucket, e, lo, hi);
    }
  }
  k_post<<<(n + 255) / 256, 256, 0, stream>>>(cursor, bucket, dis, n);

  // 3 GCN layers. proj(h_l) fused into gemm(l+1) which re-reads h_l as A;
  // first fused proj WRITES out (+lin_b), second accumulates; proj(h_3)
  // standalone (no successor gemm).
  const int gtiles = (n + 127) / 128;   // 512-thr gemm: 128 rows/block
  const int ptiles = (n + 63) / 64;
  k_gemm_mfma<false, 0><<<gtiles, 512, 0, stream>>>(
      x, wth, wtl, tbuf, dis, nullptr, nullptr, nullptr, nullptr, n);
  k_agg<<<2048, 256, 0, stream>>>(tbuf, cursor, bucket, dis, bs, hbuf, n);
  k_gemm_mfma<true, 1><<<gtiles, 512, 0, stream>>>(
      hbuf, wth + (size_t)1 * HDIM * HDIM, wtl + (size_t)1 * HDIM * HDIM,
      tbuf, dis, lwth, lwtl, lb, out, n);
  k_agg<<<2048, 256, 0, stream>>>(
      tbuf, cursor, bucket, dis, bs + (size_t)1 * HDIM, hbuf, n);
  k_gemm_mfma<true, 2><<<gtiles, 512, 0, stream>>>(
      hbuf, wth + (size_t)2 * HDIM * HDIM, wtl + (size_t)2 * HDIM * HDIM,
      tbuf, dis, lwth + (size_t)1 * RDIM * HDIM, lwtl + (size_t)1 * RDIM * HDIM,
      nullptr, out, n);
  k_agg<<<2048, 256, 0, stream>>>(
      tbuf, cursor, bucket, dis, bs + (size_t)2 * HDIM, hbuf, n);
  k_proj<<<ptiles, 256, 0, stream>>>(
      hbuf, lwth + (size_t)2 * RDIM * HDIM, lwtl + (size_t)2 * RDIM * HDIM,
      out, n);
}